// Round 6
// baseline (534.975 us; speedup 1.0000x reference)
//
#include <hip/hip_runtime.h>
#include <hip/hip_bf16.h>
#include <hip/hip_fp16.h>
#include <math.h>

typedef __hip_bfloat16 bf16;
#define NEG_SLOPE 0.2f

typedef _Float16 f16x8 __attribute__((ext_vector_type(8)));
typedef float f32x4 __attribute__((ext_vector_type(4)));

// ====== dtype detect (1 block; zeroing now done by hipMemsetAsync) ===========
__global__ void k_detect(const unsigned short* __restrict__ x, int* __restrict__ flag) {
    __shared__ int cnt;
    if (threadIdx.x == 0) cnt = 0;
    __syncthreads();
    int local = 0;
    for (int i = threadIdx.x; i < 2048; i += blockDim.x) {
        unsigned short w = x[2 * i];
        int e = (w >> 7) & 0xFF;
        if (e >= 0x90) local++;
    }
    atomicAdd(&cnt, local);
    __syncthreads();
    if (threadIdx.x == 0) flag[0] = (cnt > 100) ? 1 : 0;  // 1 => inputs are f32
}

#define NSEG 25
struct Seg { const void* src; int n; int off; };
struct Tab { Seg s[NSEG]; };

__device__ __forceinline__ float ldconv(const void* src, int i, int f32mode) {
    return f32mode ? ((const float*)src)[i]
                   : __bfloat162float(((const bf16*)src)[i]);
}

// ====== convert weights fp32 + transposed f16 weights + degree/rank ==========
__global__ void k_convert(Tab tab, float* __restrict__ dst, const int* __restrict__ flag,
                          const int* __restrict__ dstArr, int E, int N,
                          int* __restrict__ deg, int* __restrict__ rank,
                          const void* a2WlS, const void* a2WrS,
                          const void* gWlS, const void* gWrS,
                          __half* __restrict__ a2Wlt, __half* __restrict__ a2Wrt,
                          __half* __restrict__ gWlt, __half* __restrict__ gWrt) {
    int f32mode = flag[0];
    int gid = blockIdx.x * blockDim.x + threadIdx.x;
    int gsz = gridDim.x * blockDim.x;
    for (int s = 0; s < NSEG; s++) {
        Seg sg = tab.s[s];
        for (int i = gid; i < sg.n; i += gsz) {
            dst[sg.off + i] = ldconv(sg.src, i, f32mode);
        }
    }
    // transposed f16 weights: Wt[j][k] = W[k][j]
    for (int i = gid; i < 128 * 128; i += gsz) {
        int k = i >> 7, j = i & 127;
        a2Wlt[(size_t)j * 128 + k] = __float2half(ldconv(a2WlS, i, f32mode));
        a2Wrt[(size_t)j * 128 + k] = __float2half(ldconv(a2WrS, i, f32mode));
    }
    for (int i = gid; i < 128 * 32; i += gsz) {
        int k = i >> 5, j = i & 31;
        gWlt[(size_t)j * 128 + k] = __float2half(ldconv(gWlS, i, f32mode));
        gWrt[(size_t)j * 128 + k] = __float2half(ldconv(gWrS, i, f32mode));
    }
    int EA = E + N;
    for (int e = gid; e < EA; e += gsz) {
        int d = (e < E) ? dstArr[e] : (e - E);
        rank[e] = atomicAdd(&deg[d], 1);
    }
}

// ====== fused: scan (block 0) + CSR fill (spin on flag) + embed+conv1 ========
// Grid: [0] = scan block; [1, EB] = embed blocks; [EB+1, EB+FBLK] = fill blocks.
// Embed blocks never read offs -> run immediately, overlapping the scan.
__launch_bounds__(256)
__global__ void k_fill_embedlin(const int* __restrict__ srcArr, const int* __restrict__ dstArr,
                                int E, int N, const int* __restrict__ deg,
                                int* __restrict__ offs, int* __restrict__ scanflag,
                                const int* __restrict__ rank, int* __restrict__ csr,
                                const void* __restrict__ xraw, const int* __restrict__ flag,
                                const float* __restrict__ aeW, const float* __restrict__ aeb,
                                const float* __restrict__ Wl, const float* __restrict__ bl,
                                const float* __restrict__ Wr, const float* __restrict__ br,
                                __half* __restrict__ outl, float* __restrict__ outr,
                                int EB) {
    if (blockIdx.x == 0) {
        // ---- exclusive scan of deg[0..N) into offs, 256 thr x 4 elem/tile ----
        __shared__ int wsum[4];
        __shared__ int carry_s;
        int t = threadIdx.x;
        int lane = t & 63, wid = t >> 6;
        if (t == 0) carry_s = 0;
        __syncthreads();
        int nt = (N + 1023) >> 10;
        for (int tile = 0; tile < nt; tile++) {
            int i0 = tile * 1024 + t * 4;
            int4 v = {0, 0, 0, 0};
            if (i0 + 3 < N) v = *(const int4*)&deg[i0];
            else {
                if (i0     < N) v.x = deg[i0];
                if (i0 + 1 < N) v.y = deg[i0 + 1];
                if (i0 + 2 < N) v.z = deg[i0 + 2];
                if (i0 + 3 < N) v.w = deg[i0 + 3];
            }
            int s4 = v.x + v.y + v.z + v.w;
            int x = s4;
            #pragma unroll
            for (int o = 1; o < 64; o <<= 1) {
                int y = __shfl_up(x, o);
                if (lane >= o) x += y;
            }
            if (lane == 63) wsum[wid] = x;
            __syncthreads();
            int wpre = 0;
            #pragma unroll
            for (int w = 0; w < 4; w++) if (w < wid) wpre += wsum[w];
            int tot = wsum[0] + wsum[1] + wsum[2] + wsum[3];
            int cprev = carry_s;
            int pre = cprev + wpre + (x - s4);
            if (i0     < N) offs[i0]     = pre;
            if (i0 + 1 < N) offs[i0 + 1] = pre + v.x;
            if (i0 + 2 < N) offs[i0 + 2] = pre + v.x + v.y;
            if (i0 + 3 < N) offs[i0 + 3] = pre + v.x + v.y + v.z;
            __syncthreads();
            if (t == 0) carry_s = cprev + tot;
            // next tile's first __syncthreads() orders this update
        }
        __syncthreads();
        if (t == 0) {
            offs[N] = carry_s;
            __threadfence();
            __hip_atomic_store(scanflag, 1, __ATOMIC_RELEASE, __HIP_MEMORY_SCOPE_AGENT);
        }
        return;
    }
    if (blockIdx.x > EB) {
        // ---- CSR fill: wait for scan, then scatter via captured rank ----
        if (threadIdx.x == 0) {
            while (__hip_atomic_load(scanflag, __ATOMIC_ACQUIRE,
                                     __HIP_MEMORY_SCOPE_AGENT) == 0)
                __builtin_amdgcn_s_sleep(8);
        }
        __syncthreads();
        int e = (blockIdx.x - EB - 1) * 256 + threadIdx.x;
        int EA = E + N;
        if (e >= EA) return;
        int d, s;
        if (e < E) { d = dstArr[e]; s = srcArr[e]; } else { d = s = e - E; }
        csr[offs[d] + rank[e]] = s;     // no atomics: rank captured during count
        return;
    }
    // ---- embed + conv1 linear for 32 nodes (no dependency on scan) ----
    __shared__ float xs[100 * 36];
    __shared__ float axs[32 * 36];
    constexpr int NTP = 36;
    int t = threadIdx.x, nb = (blockIdx.x - 1) * 32;
    if (flag[0]) {
        const float4* x4 = (const float4*)xraw;
        for (int idx = t; idx < 32 * 25; idx += 256) {
            int node = idx / 25, k4 = idx % 25;
            float4 v = x4[(size_t)(nb + node) * 25 + k4];
            xs[(k4 * 4 + 0) * NTP + node] = v.x;
            xs[(k4 * 4 + 1) * NTP + node] = v.y;
            xs[(k4 * 4 + 2) * NTP + node] = v.z;
            xs[(k4 * 4 + 3) * NTP + node] = v.w;
        }
    } else {
        const ushort4* xu = (const ushort4*)xraw;
        for (int idx = t; idx < 32 * 25; idx += 256) {
            int node = idx / 25, k4 = idx % 25;
            ushort4 u = xu[(size_t)(nb + node) * 25 + k4];
            xs[(k4 * 4 + 0) * NTP + node] = __uint_as_float((unsigned)u.x << 16);
            xs[(k4 * 4 + 1) * NTP + node] = __uint_as_float((unsigned)u.y << 16);
            xs[(k4 * 4 + 2) * NTP + node] = __uint_as_float((unsigned)u.z << 16);
            xs[(k4 * 4 + 3) * NTP + node] = __uint_as_float((unsigned)u.w << 16);
        }
    }
    __syncthreads();
    {
        int j = t & 31, g0 = t >> 5;
        float a0 = 0.f, a1 = 0.f, a2 = 0.f, a3 = 0.f;
        #pragma unroll 10
        for (int k = 0; k < 100; k++) {
            float w = aeW[k * 32 + j];
            const float4 xv = *(const float4*)&xs[k * NTP + g0 * 4];
            a0 += w * xv.x; a1 += w * xv.y; a2 += w * xv.z; a3 += w * xv.w;
        }
        float bj = aeb[j];
        axs[j * NTP + g0 * 4 + 0] = fmaxf(a0 + bj, 0.f);
        axs[j * NTP + g0 * 4 + 1] = fmaxf(a1 + bj, 0.f);
        axs[j * NTP + g0 * 4 + 2] = fmaxf(a2 + bj, 0.f);
        axs[j * NTP + g0 * 4 + 3] = fmaxf(a3 + bj, 0.f);
    }
    __syncthreads();
    {
        int j = t & 63, g0 = t >> 6;
        float aL0[2][4], aL1[2][4], aR0[2][4], aR1[2][4];
        #pragma unroll
        for (int g = 0; g < 2; g++)
            #pragma unroll
            for (int c = 0; c < 4; c++) { aL0[g][c]=0.f; aL1[g][c]=0.f; aR0[g][c]=0.f; aR1[g][c]=0.f; }
        #pragma unroll 4
        for (int k = 0; k < 32; k++) {
            float wl0 = Wl[k * 128 + j];
            float wl1 = Wl[k * 128 + j + 64];
            float wr0 = Wr[k * 128 + j];
            float wr1 = Wr[k * 128 + j + 64];
            #pragma unroll
            for (int g = 0; g < 2; g++) {
                const float4 xv = *(const float4*)&axs[k * NTP + (g0 + g * 4) * 4];
                aL0[g][0] += wl0 * xv.x; aL0[g][1] += wl0 * xv.y; aL0[g][2] += wl0 * xv.z; aL0[g][3] += wl0 * xv.w;
                aL1[g][0] += wl1 * xv.x; aL1[g][1] += wl1 * xv.y; aL1[g][2] += wl1 * xv.z; aL1[g][3] += wl1 * xv.w;
                aR0[g][0] += wr0 * xv.x; aR0[g][1] += wr0 * xv.y; aR0[g][2] += wr0 * xv.z; aR0[g][3] += wr0 * xv.w;
                aR1[g][0] += wr1 * xv.x; aR1[g][1] += wr1 * xv.y; aR1[g][2] += wr1 * xv.z; aR1[g][3] += wr1 * xv.w;
            }
        }
        float bl0 = bl[j], bl1 = bl[j + 64], br0 = br[j], br1 = br[j + 64];
        #pragma unroll
        for (int g = 0; g < 2; g++) {
            int n0 = nb + (g0 + g * 4) * 4;
            #pragma unroll
            for (int c = 0; c < 4; c++) {
                size_t row = (size_t)(n0 + c) * 128;
                outl[row + j]      = __float2half(aL0[g][c] + bl0);
                outl[row + j + 64] = __float2half(aL1[g][c] + bl1);
                outr[row + j]      = aR0[g][c] + br0;
                outr[row + j + 64] = aR1[g][c] + br1;
            }
        }
    }
}

// ====== per-edge math (16-lane group, 8 channels/lane) =======================
__device__ __forceinline__ void gat_proc(float4 raw, bool valid,
                                         const float* xrd, const float* av,
                                         float* acc, float& sm) {
    const __half2* h = (const __half2*)&raw;
    float v[8];
    float2 f;
    f = __half22float2(h[0]); v[0] = f.x; v[1] = f.y;
    f = __half22float2(h[1]); v[2] = f.x; v[3] = f.y;
    f = __half22float2(h[2]); v[4] = f.x; v[5] = f.y;
    f = __half22float2(h[3]); v[6] = f.x; v[7] = f.y;
    float p = 0.f;
    #pragma unroll
    for (int c = 0; c < 8; c++) {
        float u = v[c] + xrd[c];
        u = (u > 0.f) ? u : NEG_SLOPE * u;
        p += u * av[c];
    }
    p += __shfl_xor(p, 1);
    p += __shfl_xor(p, 2);
    p += __shfl_xor(p, 4);
    p += __shfl_xor(p, 8);
    float w = __expf(fminf(p, 80.f));
    if (!valid) w = 0.f;
    sm += w;
    #pragma unroll
    for (int c = 0; c < 8; c++) acc[c] += w * v[c];
}

// ====== GAT H=4 gather of ONE dst per 16-lane group into LDS row `node` =====
// xrp: pointer to this dst's 128-float xr row (global or LDS).
// d < 0 => inactive group (zeros written).
// xsh layout: xsh[node * 136 + ch], node in [0,16), ch in [0,128). 4.35 KB.
__device__ __forceinline__ void gat16_to_lds(__half* xsh,
                                             const __half* __restrict__ xl,
                                             const float* xrp,
                                             const float* __restrict__ att,
                                             const int* __restrict__ offs,
                                             const int* __restrict__ csr,
                                             const float* __restrict__ bias,
                                             int d, int node) {
    int t = threadIdx.x;
    int lane = t & 63;
    int sub = lane & 15;                      // lane within group
    int lb = lane & 48;                       // group base lane
    float av[8];
    {
        const float4* t4 = (const float4*)(att + sub * 8);
        float4 c = t4[0], e = t4[1];
        av[0]=c.x; av[1]=c.y; av[2]=c.z; av[3]=c.w;
        av[4]=e.x; av[5]=e.y; av[6]=e.z; av[7]=e.w;
    }
    bool ok = d >= 0;
    int i0 = ok ? offs[d] : 0;
    int i1 = ok ? offs[d + 1] : 0;
    int cnt = i1 - i0;

    float xrd[8];
    #pragma unroll
    for (int c = 0; c < 8; c++) xrd[c] = 0.f;
    if (ok) {
        const float4* p4 = (const float4*)(xrp + sub * 8);
        float4 a = p4[0], b = p4[1];
        xrd[0]=a.x; xrd[1]=a.y; xrd[2]=a.z; xrd[3]=a.w;
        xrd[4]=b.x; xrd[5]=b.y; xrd[6]=b.z; xrd[7]=b.w;
    }
    float acc[8];
    #pragma unroll
    for (int c = 0; c < 8; c++) acc[c] = 0.f;
    float sm = 0.f;

    // first csr chunk (16 edges, one coalesced 64B load per group)
    int myv = (sub < cnt) ? csr[i0 + sub] : 0;
    for (int c0 = 0; c0 < cnt; c0 += 16) {
        // prefetch next chunk's indices while processing current
        int myv_nxt = (c0 + 16 + sub < cnt) ? csr[i0 + c0 + 16 + sub] : 0;
        int rem = min(cnt - c0, 16);
        for (int k = 0; k < rem; k += 4) {
            int s0 = __shfl(myv, lb + k + 0);
            int s1 = __shfl(myv, lb + k + 1);
            int s2 = __shfl(myv, lb + k + 2);
            int s3 = __shfl(myv, lb + k + 3);
            float4 r0 = *(const float4*)(xl + (size_t)s0 * 128 + sub * 8);
            float4 r1 = *(const float4*)(xl + (size_t)s1 * 128 + sub * 8);
            float4 r2 = *(const float4*)(xl + (size_t)s2 * 128 + sub * 8);
            float4 r3 = *(const float4*)(xl + (size_t)s3 * 128 + sub * 8);
            gat_proc(r0, true,        xrd, av, acc, sm);
            gat_proc(r1, k + 1 < rem, xrd, av, acc, sm);
            gat_proc(r2, k + 2 < rem, xrd, av, acc, sm);
            gat_proc(r3, k + 3 < rem, xrd, av, acc, sm);
        }
        myv = myv_nxt;
    }

    // acc is already the full per-dst sum (group's 16 lanes cover 128 ch)
    int ch = sub * 8;
    if (ok) {
        float inv = 1.f / (sm + 1e-16f);
        #pragma unroll
        for (int c = 0; c < 8; c += 2) {
            __half2 hv;
            hv.x = __float2half(fmaxf(acc[c]     * inv + bias[ch + c],     0.f));
            hv.y = __float2half(fmaxf(acc[c + 1] * inv + bias[ch + c + 1], 0.f));
            *(__half2*)&xsh[node * 136 + ch + c] = hv;
        }
    } else {
        // keep MFMA inputs clean for unused rows
        #pragma unroll
        for (int c = 0; c < 8; c += 2)
            *(__half2*)&xsh[node * 136 + ch + c] = __half2{__half(0.f), __half(0.f)};
    }
}

// ====== fused: conv1 gather (16-dst tile) -> conv2 L-linear via MFMA =========
// R-side (a2Wr) is NOT computed here (only needed at ~1100 L-list dsts);
// instead the raw gathered f1 tile is stored fp16 for k_gatling to use.
// Extra block (blockIdx == GT) builds the focal-neighborhood dst list L.
__launch_bounds__(256)
__global__ void k_gatlin(const __half* __restrict__ xl, const float* __restrict__ xr,
                         const float* __restrict__ att,
                         const int* __restrict__ offs, const int* __restrict__ csr,
                         const float* __restrict__ bias,
                         const __half* __restrict__ Wlt, const float* __restrict__ bl,
                         __half* __restrict__ outl, __half* __restrict__ outf1, int N,
                         const int* __restrict__ focal, int B,
                         int* __restrict__ L, int* __restrict__ Lcnt, int GT) {
    if (blockIdx.x >= GT) {
        int t = threadIdx.x;
        if (t < B) {
            int f = focal[t];
            int j0 = offs[f], j1 = offs[f + 1];
            int base = atomicAdd(Lcnt, j1 - j0);
            for (int j = j0; j < j1; j++) L[base + (j - j0)] = csr[j];
        }
        return;
    }
    __shared__ __align__(16) __half xsh[16 * 136];
    int nb = blockIdx.x * 16;
    int t = threadIdx.x;
    int lane = t & 63, wv = t >> 6;
    int quad = lane >> 4, n16 = lane & 15;
    {
        int node = wv * 4 + quad;
        int dd = nb + node;
        bool okd = dd < N;
        const float* xrp = xr + (size_t)(okd ? dd : 0) * 128;
        gat16_to_lds(xsh, xl, xrp, att, offs, csr, bias, okd ? dd : -1, node);
    }
    __syncthreads();

    // write raw f1 tile out (fp16) for the sparse R-side reconstruction
    {
        int node = t >> 4, ch = (t & 15) * 8;
        if (nb + node < N)
            *(f16x8*)&outf1[(size_t)(nb + node) * 128 + ch] =
                *(const f16x8*)&xsh[node * 136 + ch];
    }

    // A fragments: A[m=lane&15][k=quad*8+i], 4 k-tiles of 32
    f16x8 a[4];
    #pragma unroll
    for (int kt = 0; kt < 4; kt++)
        a[kt] = *(const f16x8*)&xsh[n16 * 136 + kt * 32 + quad * 8];

    int j0 = wv * 32;   // this wave's 32 output columns (two 16-tiles), L only
    f32x4 aL0 = {0.f,0.f,0.f,0.f}, aL1 = {0.f,0.f,0.f,0.f};
    #pragma unroll
    for (int kt = 0; kt < 4; kt++) {
        int ko = kt * 32 + quad * 8;
        f16x8 b0 = *(const f16x8*)&Wlt[(size_t)(j0 + n16) * 128 + ko];
        f16x8 b1 = *(const f16x8*)&Wlt[(size_t)(j0 + 16 + n16) * 128 + ko];
        aL0 = __builtin_amdgcn_mfma_f32_16x16x32_f16(a[kt], b0, aL0, 0, 0, 0);
        aL1 = __builtin_amdgcn_mfma_f32_16x16x32_f16(a[kt], b1, aL1, 0, 0, 0);
    }
    float blj0 = bl[j0 + n16], blj1 = bl[j0 + 16 + n16];
    #pragma unroll
    for (int r = 0; r < 4; r++) {
        int node = quad * 4 + r;        // D row = node
        if (nb + node >= N) continue;
        size_t row = (size_t)(nb + node) * 128;
        outl[row + j0 + n16]      = __float2half(aL0[r] + blj0);
        outl[row + j0 + 16 + n16] = __float2half(aL1[r] + blj1);
    }
}

// ====== sparse: conv2 xr-on-the-fly + gather + global linear at L dsts =======
// Phase A: xr2 = f1[tile dsts] @ a2Wr + a2br (MFMA, into LDS) — bit-identical
// to the old dense path (same fp16 operands). Phase B: conv2-GAT gather.
// Phase C: global linear (gW). L has ~B*deg ~= 1100 dsts.
__launch_bounds__(256)
__global__ void k_gatling(const __half* __restrict__ xl,      // hxl2 [N,128] f16
                          const __half* __restrict__ hf1,     // f1 [N,128] f16
                          const __half* __restrict__ Wrt2,    // a2Wrt [128][128]
                          const float* __restrict__ br2,      // a2br [128]
                          const float* __restrict__ att,
                          const int* __restrict__ offs, const int* __restrict__ csr,
                          const float* __restrict__ bias,
                          const __half* __restrict__ Wlt, const float* __restrict__ bl,
                          const __half* __restrict__ Wrt, const float* __restrict__ br,
                          __half* __restrict__ outl, float* __restrict__ outr,
                          const int* __restrict__ L, const int* __restrict__ Lcnt) {
    __shared__ __align__(16) __half xsh[16 * 136];
    __shared__ __align__(16) float xr2[16 * 132];
    int total = *Lcnt;
    int t = threadIdx.x;
    int lane = t & 63, wv = t >> 6;
    int quad = lane >> 4, n16 = lane & 15;

    for (int tile = blockIdx.x; tile * 16 < total; tile += gridDim.x) {
        if (tile != (int)blockIdx.x) __syncthreads();   // LDS reuse guard
        // ---- phase A: xr2 = f1 @ a2Wr + a2br for the 16 tile dsts ----
        {
            int ia = tile * 16 + n16;
            int da = (ia < total) ? L[ia] : -1;
            f16x8 af[4];
            if (da >= 0) {
                #pragma unroll
                for (int kt = 0; kt < 4; kt++)
                    af[kt] = *(const f16x8*)&hf1[(size_t)da * 128 + kt * 32 + quad * 8];
            } else {
                #pragma unroll
                for (int kt = 0; kt < 4; kt++)
                    #pragma unroll
                    for (int c = 0; c < 8; c++) af[kt][c] = (_Float16)0;
            }
            f32x4 ar0 = {0.f,0.f,0.f,0.f}, ar1 = {0.f,0.f,0.f,0.f};
            #pragma unroll
            for (int kt = 0; kt < 4; kt++) {
                int ko = kt * 32 + quad * 8;
                f16x8 b0 = *(const f16x8*)&Wrt2[(size_t)(wv * 32 + n16) * 128 + ko];
                f16x8 b1 = *(const f16x8*)&Wrt2[(size_t)(wv * 32 + 16 + n16) * 128 + ko];
                ar0 = __builtin_amdgcn_mfma_f32_16x16x32_f16(af[kt], b0, ar0, 0, 0, 0);
                ar1 = __builtin_amdgcn_mfma_f32_16x16x32_f16(af[kt], b1, ar1, 0, 0, 0);
            }
            int c0 = wv * 32 + n16, c1 = wv * 32 + 16 + n16;
            float bb0 = br2[c0], bb1 = br2[c1];
            #pragma unroll
            for (int r = 0; r < 4; r++) {
                int row = quad * 4 + r;
                xr2[row * 132 + c0] = ar0[r] + bb0;
                xr2[row * 132 + c1] = ar1[r] + bb1;
            }
        }
        __syncthreads();
        // ---- phase B: conv2-GAT gather for this tile into xsh ----
        int node = wv * 4 + quad;
        int idx = tile * 16 + node;
        int d = (idx < total) ? L[idx] : -1;
        gat16_to_lds(xsh, xl, &xr2[node * 132], att, offs, csr, bias, d, node);
        __syncthreads();
        // ---- phase C: global linear (FOUT=32, L and R) ----
        f16x8 a[4];
        #pragma unroll
        for (int kt = 0; kt < 4; kt++)
            a[kt] = *(const f16x8*)&xsh[n16 * 136 + kt * 32 + quad * 8];

        const __half* Wt = (wv < 2) ? Wlt : Wrt;
        int j0 = (wv & 1) * 16;
        f32x4 accv = {0.f,0.f,0.f,0.f};
        #pragma unroll
        for (int kt = 0; kt < 4; kt++) {
            f16x8 b = *(const f16x8*)&Wt[(size_t)(j0 + n16) * 128 + kt * 32 + quad * 8];
            accv = __builtin_amdgcn_mfma_f32_16x16x32_f16(a[kt], b, accv, 0, 0, 0);
        }
        float bj = ((wv < 2) ? bl : br)[j0 + n16];
        #pragma unroll
        for (int r = 0; r < 4; r++) {
            int nn = quad * 4 + r;
            int gidx = tile * 16 + nn;
            if (gidx >= total) continue;
            int gd = L[gidx];              // duplicates write identical values
            size_t row = (size_t)gd * 32;
            if (wv < 2) outl[row + j0 + n16] = __float2half(accv[r] + bj);
            else        outr[row + j0 + n16] = accv[r] + bj;
        }
    }
}

// ===== tail: global-GAT gather for the 64 FOCAL dsts only + output head =====
__launch_bounds__(64)
__global__ void k_tailf(const __half* __restrict__ xl, const float* __restrict__ xr,
                        const float* __restrict__ att,
                        const int* __restrict__ offs, const int* __restrict__ csr,
                        const float* __restrict__ gb, const int* __restrict__ focal,
                        const float* __restrict__ clf, const float* __restrict__ clW,
                        const float* __restrict__ clb, const float* __restrict__ fcW,
                        const float* __restrict__ fcb, void* __restrict__ out,
                        const int* __restrict__ flag) {
    __shared__ float comb[64];
    __shared__ float ssb[2];
    int b = blockIdx.x;
    int t = threadIdx.x;                  // 64
    int d = focal[b];
    int grp = t >> 3, sub = t & 7;        // 8 edge-groups x 8 lanes (4 ch each)
    int i0 = offs[d], i1 = offs[d + 1];

    float xrd[4], av[4], acc[4];
    {
        float4 a = *(const float4*)(xr + (size_t)d * 32 + sub * 4);
        xrd[0]=a.x; xrd[1]=a.y; xrd[2]=a.z; xrd[3]=a.w;
        float4 c = *(const float4*)(att + sub * 4);
        av[0]=c.x; av[1]=c.y; av[2]=c.z; av[3]=c.w;
    }
    #pragma unroll
    for (int c = 0; c < 4; c++) acc[c] = 0.f;
    float sm = 0.f;

    for (int i = i0 + grp; i < i1; i += 8) {
        float2 raw = *(const float2*)(xl + (size_t)csr[i] * 32 + sub * 4);
        const __half2* h = (const __half2*)&raw;
        float v[4];
        float2 f;
        f = __half22float2(h[0]); v[0] = f.x; v[1] = f.y;
        f = __half22float2(h[1]); v[2] = f.x; v[3] = f.y;
        float p = 0.f;
        #pragma unroll
        for (int c = 0; c < 4; c++) {
            float u = v[c] + xrd[c];
            u = (u > 0.f) ? u : NEG_SLOPE * u;
            p += u * av[c];
        }
        p += __shfl_xor(p, 1);
        p += __shfl_xor(p, 2);
        p += __shfl_xor(p, 4);
        float w = __expf(fminf(p, 80.f));
        sm += w;
        #pragma unroll
        for (int c = 0; c < 4; c++) acc[c] += w * v[c];
    }
    // merge 8 edge-groups
    sm += __shfl_xor(sm, 8); sm += __shfl_xor(sm, 16); sm += __shfl_xor(sm, 32);
    #pragma unroll
    for (int c = 0; c < 4; c++) {
        acc[c] += __shfl_xor(acc[c], 8);
        acc[c] += __shfl_xor(acc[c], 16);
        acc[c] += __shfl_xor(acc[c], 32);
    }
    if (grp == 0) {
        float inv = 1.f / (sm + 1e-16f);
        #pragma unroll
        for (int c = 0; c < 4; c++)
            comb[sub * 4 + c] = fmaxf(acc[c] * inv + gb[sub * 4 + c], 0.f);
    }
    if (t < 2) {
        float s = 0.f;
        for (int l = 0; l < 50; l++) s += clf[(size_t)b * 100 + l * 2 + t];
        ssb[t] = s / 50.f;
    }
    __syncthreads();
    if (t < 32) comb[32 + t] = ssb[0] * clW[t] + ssb[1] * clW[32 + t] + clb[t];
    __syncthreads();
    if (t < 60) {
        float a2 = fcb[t];
        #pragma unroll 16
        for (int k = 0; k < 64; k++) a2 += comb[k] * fcW[k * 60 + t];
        if (flag[0]) ((float*)out)[b * 60 + t] = a2;
        else ((bf16*)out)[b * 60 + t] = __float2bfloat16(a2);
    }
}

extern "C" void kernel_launch(void* const* d_in, const int* in_sizes, int n_in,
                              void* d_out, int out_size, void* d_ws, size_t ws_size,
                              hipStream_t stream) {
    const int* edge  = (const int*)d_in[1];
    const int* focal = (const int*)d_in[5];

    const int N = in_sizes[0] / 100;   // 20000
    const int E = in_sizes[1] / 2;     // 320000
    const int B = in_sizes[5];         // 64
    const int EA = E + N;
    const int* srcArr = edge;
    const int* dstArr = edge + E;

    // ---- conversion table: weights + centerlines -> fp32 in ws (x stays raw)
    const int idxs[NSEG] = {7,8,9,10,11,12,13,14,15,16,17,18,19,20,
                            35,36,37,38,39,40,41,42,43,44, 6};
    float* base = (float*)d_ws;
    int* flag = (int*)base;            // base[0..15] reserved
    float* wf = base + 16;
    Tab tab;
    int off[NSEG];
    int o = 0;
    for (int i = 0; i < NSEG; i++) {
        tab.s[i].src = d_in[idxs[i]];
        tab.s[i].n   = in_sizes[idxs[i]];
        tab.s[i].off = o;
        off[i] = o;
        o += in_sizes[idxs[i]];
    }
    const float* aeW  = wf + off[0],  *aeb  = wf + off[1];
    const float* a1Wl = wf + off[2],  *a1bl = wf + off[3];
    const float* a1Wr = wf + off[4],  *a1br = wf + off[5];
    const float* a1att= wf + off[6],  *a1b  = wf + off[7];
    const float* a2bl = wf + off[9];
    const float* a2br = wf + off[11];
    const float* a2att= wf + off[12], *a2b  = wf + off[13];
    const float* clW  = wf + off[14], *clb  = wf + off[15];
    const float* gbl  = wf + off[17];
    const float* gbr  = wf + off[19];
    const float* gatt = wf + off[20], *gb   = wf + off[21];
    const float* fcW  = wf + off[22], *fcb  = wf + off[23];
    const float* clf  = wf + off[24];

    // ---- remaining workspace (keep 16B alignment) ----
    float* p = wf + o + ((4 - (o & 3)) & 3);
    size_t N128 = (size_t)N * 128;
    __half* hxl1 = (__half*)p;      p += (size_t)N * 64;    // conv1 xl fp16 [N,128]; later global xl [N,32]
    float* fB1  = p;                p += N128;              // conv1 xr fp32; later global xrg [N,32]
    __half* hxl2 = (__half*)p;      p += (size_t)N * 64;    // conv2 xl fp16 [N,128]
    __half* hf1  = (__half*)p;      p += (size_t)N * 64;    // raw conv1 output f1 fp16 [N,128]
    int* deg    = (int*)p;          // [N]
    int* st     = deg + N;          // [32] aux ints; st[30] = Lcnt, st[31] = scanflag
    int* offs   = st + 32;          // N+1
    int* rank   = offs + N + 1;     // EA
    int* csr    = rank + EA;        // EA (src node ids)
    // transposed f16 weights (16B aligned)
    uintptr_t up = (uintptr_t)(csr + EA);
    up = (up + 15) & ~(uintptr_t)15;
    __half* a2Wlt = (__half*)up;    // [128][128]
    __half* a2Wrt = a2Wlt + 16384;  // [128][128]
    __half* gWlt  = a2Wrt + 16384;  // [32][128]
    __half* gWrt  = gWlt + 4096;    // [32][128]
    int* Lbuf = (int*)(gWrt + 4096);   // focal-neighborhood dst list (<= EA)
    int* Lcnt = st + 30;
    int* scanflag = st + 31;

    const int EB = N / 32;                     // embedlin blocks (625)
    const int FBLK = (EA + 255) / 256;         // fill blocks
    const int GT = (N + 15) / 16;              // fused gather+linear tiles (1250)

    // ---- zero deg/aux via DMA + tiny dtype-detect kernel ----
    hipMemsetAsync(deg, 0, (size_t)(N + 32) * sizeof(int), stream);
    k_detect<<<1, 256, 0, stream>>>((const unsigned short*)d_in[0], flag);
    // ---- convert weights (+ f16 transposed) + degree count with rank capture
    k_convert<<<256, 256, 0, stream>>>(tab, wf, flag, dstArr, E, N, deg, rank,
                                       d_in[15], d_in[17], d_in[37], d_in[39],
                                       a2Wlt, a2Wrt, gWlt, gWrt);
    // ---- fused: scan (block 0) + CSR fill (spin) + embed+conv1 -> hxl1/fB1 --
    k_fill_embedlin<<<1 + EB + FBLK, 256, 0, stream>>>(srcArr, dstArr, E, N, deg,
                                                       offs, scanflag, rank, csr,
                                                       d_in[0], flag, aeW, aeb,
                                                       a1Wl, a1bl, a1Wr, a1br,
                                                       hxl1, fB1, EB);
    // ---- conv1 gather + conv2 L-linear (MFMA) -> hxl2, f1 -> hf1; +L build --
    k_gatlin<<<GT + 1, 256, 0, stream>>>(hxl1, fB1, a1att, offs, csr, a1b,
                                         a2Wlt, a2bl, hxl2, hf1, N,
                                         focal, B, Lbuf, Lcnt, GT);
    // ---- SPARSE: xr2 on-the-fly + conv2 gather + global linear over L -------
    k_gatling<<<128, 256, 0, stream>>>(hxl2, hf1, a2Wrt, a2br, a2att, offs, csr, a2b,
                                       gWlt, gbl, gWrt, gbr, hxl1, fB1, Lbuf, Lcnt);
    // ---- tail: global gather for the 64 focal dsts + head ----
    k_tailf<<<B, 64, 0, stream>>>(hxl1, fB1, gatt, offs, csr, gb, focal,
                                  clf, clW, clb, fcW, fcb, d_out, flag);
}

// Round 7
// 255.140 us; speedup vs baseline: 2.0968x; 2.0968x over previous
//
#include <hip/hip_runtime.h>
#include <hip/hip_bf16.h>
#include <hip/hip_fp16.h>
#include <math.h>

typedef __hip_bfloat16 bf16;
#define NEG_SLOPE 0.2f
#define SFLAG (1 << 30)

typedef _Float16 f16x8 __attribute__((ext_vector_type(8)));
typedef float f32x4 __attribute__((ext_vector_type(4)));

#define NSEG 25
struct Seg { const void* src; int n; int off; };
struct Tab { Seg s[NSEG]; };

__device__ __forceinline__ float ldconv(const void* src, int i, int f32mode) {
    return f32mode ? ((const float*)src)[i]
                   : __bfloat162float(((const bf16*)src)[i]);
}

// ====== convert weights fp32 + transposed f16 weights + degree/rank ==========
// dtype-detect is merged: every block recomputes the census locally (cheap,
// L2-hot); block 0 publishes flag[0] for downstream kernels.
__global__ void k_convert(Tab tab, float* __restrict__ dst,
                          const unsigned short* __restrict__ xdet, int* __restrict__ flag,
                          const int* __restrict__ dstArr, int E, int N,
                          int* __restrict__ deg, int* __restrict__ rank,
                          const void* a2WlS, const void* a2WrS,
                          const void* gWlS, const void* gWrS,
                          __half* __restrict__ a2Wlt, __half* __restrict__ a2Wrt,
                          __half* __restrict__ gWlt, __half* __restrict__ gWrt) {
    __shared__ int cnt;
    if (threadIdx.x == 0) cnt = 0;
    __syncthreads();
    int local = 0;
    for (int i = threadIdx.x; i < 2048; i += blockDim.x) {
        unsigned short w = xdet[2 * i];
        int e = (w >> 7) & 0xFF;
        if (e >= 0x90) local++;
    }
    atomicAdd(&cnt, local);
    __syncthreads();
    int f32mode = (cnt > 100) ? 1 : 0;          // same verdict in every block
    if (blockIdx.x == 0 && threadIdx.x == 0) flag[0] = f32mode;

    int gid = blockIdx.x * blockDim.x + threadIdx.x;
    int gsz = gridDim.x * blockDim.x;
    for (int s = 0; s < NSEG; s++) {
        Seg sg = tab.s[s];
        for (int i = gid; i < sg.n; i += gsz) {
            dst[sg.off + i] = ldconv(sg.src, i, f32mode);
        }
    }
    // transposed f16 weights: Wt[j][k] = W[k][j]
    for (int i = gid; i < 128 * 128; i += gsz) {
        int k = i >> 7, j = i & 127;
        a2Wlt[(size_t)j * 128 + k] = __float2half(ldconv(a2WlS, i, f32mode));
        a2Wrt[(size_t)j * 128 + k] = __float2half(ldconv(a2WrS, i, f32mode));
    }
    for (int i = gid; i < 128 * 32; i += gsz) {
        int k = i >> 5, j = i & 31;
        gWlt[(size_t)j * 128 + k] = __float2half(ldconv(gWlS, i, f32mode));
        gWrt[(size_t)j * 128 + k] = __float2half(ldconv(gWrS, i, f32mode));
    }
    int EA = E + N;
    for (int e = gid; e < EA; e += gsz) {
        int d = (e < E) ? dstArr[e] : (e - E);
        rank[e] = atomicAdd(&deg[d], 1);
    }
}

// ====== single-kernel chained-lookback exclusive scan ========================
__launch_bounds__(1024)
__global__ void k_scanf(const int* __restrict__ deg, int* __restrict__ offs,
                        int n, int* __restrict__ st, int nb) {
    __shared__ int ws[16];
    __shared__ int stot, sprev;
    int tile = blockIdx.x;
    int i = tile * 1024 + threadIdx.x;
    int lane = threadIdx.x & 63, wid = threadIdx.x >> 6;
    int v = (i < n) ? deg[i] : 0;
    int x = v;
    #pragma unroll
    for (int o = 1; o < 64; o <<= 1) {
        int y = __shfl_up(x, o);
        if (lane >= o) x += y;
    }
    if (lane == 63) ws[wid] = x;
    __syncthreads();
    if (wid == 0) {
        int w = (lane < 16) ? ws[lane] : 0;
        int s = w;
        #pragma unroll
        for (int o = 1; o < 16; o <<= 1) {
            int y = __shfl_up(s, o);
            if (lane >= o) s += y;
        }
        if (lane < 16) ws[lane] = s - w;
        if (lane == 15) stot = s;
    }
    __syncthreads();
    int local = ws[wid] + x - v;     // block-local exclusive
    if (threadIdx.x == 0) {
        int prev = 0;
        if (tile > 0) {
            int vv;
            while ((((vv = __hip_atomic_load(&st[tile - 1], __ATOMIC_ACQUIRE,
                                             __HIP_MEMORY_SCOPE_AGENT))) & SFLAG) == 0) {}
            prev = vv & ~SFLAG;
        }
        __hip_atomic_store(&st[tile], (prev + stot) | SFLAG, __ATOMIC_RELEASE,
                           __HIP_MEMORY_SCOPE_AGENT);
        sprev = prev;
        if (tile == nb - 1) offs[n] = prev + stot;
    }
    __syncthreads();
    if (i < n) offs[i] = sprev + local;
}

// ====== fused: CSR fill via rank (blocks >= EB) + embed+conv1-linear =========
__launch_bounds__(256)
__global__ void k_fill_embedlin(const int* __restrict__ srcArr, const int* __restrict__ dstArr,
                                int E, int N, const int* __restrict__ offs,
                                const int* __restrict__ rank, int* __restrict__ csr,
                                const void* __restrict__ xraw, const int* __restrict__ flag,
                                const float* __restrict__ aeW, const float* __restrict__ aeb,
                                const float* __restrict__ Wl, const float* __restrict__ bl,
                                const float* __restrict__ Wr, const float* __restrict__ br,
                                __half* __restrict__ outl, float* __restrict__ outr,
                                int EB) {
    __shared__ float xs[100 * 36];
    __shared__ float axs[32 * 36];
    if (blockIdx.x >= EB) {
        int e = (blockIdx.x - EB) * 256 + threadIdx.x;
        int EA = E + N;
        if (e >= EA) return;
        int d, s;
        if (e < E) { d = dstArr[e]; s = srcArr[e]; } else { d = s = e - E; }
        csr[offs[d] + rank[e]] = s;     // no atomics: rank captured during count
        return;
    }
    constexpr int NTP = 36;
    int t = threadIdx.x, nb = blockIdx.x * 32;
    if (flag[0]) {
        const float4* x4 = (const float4*)xraw;
        for (int idx = t; idx < 32 * 25; idx += 256) {
            int node = idx / 25, k4 = idx % 25;
            float4 v = x4[(size_t)(nb + node) * 25 + k4];
            xs[(k4 * 4 + 0) * NTP + node] = v.x;
            xs[(k4 * 4 + 1) * NTP + node] = v.y;
            xs[(k4 * 4 + 2) * NTP + node] = v.z;
            xs[(k4 * 4 + 3) * NTP + node] = v.w;
        }
    } else {
        const ushort4* xu = (const ushort4*)xraw;
        for (int idx = t; idx < 32 * 25; idx += 256) {
            int node = idx / 25, k4 = idx % 25;
            ushort4 u = xu[(size_t)(nb + node) * 25 + k4];
            xs[(k4 * 4 + 0) * NTP + node] = __uint_as_float((unsigned)u.x << 16);
            xs[(k4 * 4 + 1) * NTP + node] = __uint_as_float((unsigned)u.y << 16);
            xs[(k4 * 4 + 2) * NTP + node] = __uint_as_float((unsigned)u.z << 16);
            xs[(k4 * 4 + 3) * NTP + node] = __uint_as_float((unsigned)u.w << 16);
        }
    }
    __syncthreads();
    {
        int j = t & 31, g0 = t >> 5;
        float a0 = 0.f, a1 = 0.f, a2 = 0.f, a3 = 0.f;
        #pragma unroll 10
        for (int k = 0; k < 100; k++) {
            float w = aeW[k * 32 + j];
            const float4 xv = *(const float4*)&xs[k * NTP + g0 * 4];
            a0 += w * xv.x; a1 += w * xv.y; a2 += w * xv.z; a3 += w * xv.w;
        }
        float bj = aeb[j];
        axs[j * NTP + g0 * 4 + 0] = fmaxf(a0 + bj, 0.f);
        axs[j * NTP + g0 * 4 + 1] = fmaxf(a1 + bj, 0.f);
        axs[j * NTP + g0 * 4 + 2] = fmaxf(a2 + bj, 0.f);
        axs[j * NTP + g0 * 4 + 3] = fmaxf(a3 + bj, 0.f);
    }
    __syncthreads();
    {
        int j = t & 63, g0 = t >> 6;
        float aL0[2][4], aL1[2][4], aR0[2][4], aR1[2][4];
        #pragma unroll
        for (int g = 0; g < 2; g++)
            #pragma unroll
            for (int c = 0; c < 4; c++) { aL0[g][c]=0.f; aL1[g][c]=0.f; aR0[g][c]=0.f; aR1[g][c]=0.f; }
        #pragma unroll 4
        for (int k = 0; k < 32; k++) {
            float wl0 = Wl[k * 128 + j];
            float wl1 = Wl[k * 128 + j + 64];
            float wr0 = Wr[k * 128 + j];
            float wr1 = Wr[k * 128 + j + 64];
            #pragma unroll
            for (int g = 0; g < 2; g++) {
                const float4 xv = *(const float4*)&axs[k * NTP + (g0 + g * 4) * 4];
                aL0[g][0] += wl0 * xv.x; aL0[g][1] += wl0 * xv.y; aL0[g][2] += wl0 * xv.z; aL0[g][3] += wl0 * xv.w;
                aL1[g][0] += wl1 * xv.x; aL1[g][1] += wl1 * xv.y; aL1[g][2] += wl1 * xv.z; aL1[g][3] += wl1 * xv.w;
                aR0[g][0] += wr0 * xv.x; aR0[g][1] += wr0 * xv.y; aR0[g][2] += wr0 * xv.z; aR0[g][3] += wr0 * xv.w;
                aR1[g][0] += wr1 * xv.x; aR1[g][1] += wr1 * xv.y; aR1[g][2] += wr1 * xv.z; aR1[g][3] += wr1 * xv.w;
            }
        }
        float bl0 = bl[j], bl1 = bl[j + 64], br0 = br[j], br1 = br[j + 64];
        #pragma unroll
        for (int g = 0; g < 2; g++) {
            int n0 = nb + (g0 + g * 4) * 4;
            #pragma unroll
            for (int c = 0; c < 4; c++) {
                size_t row = (size_t)(n0 + c) * 128;
                outl[row + j]      = __float2half(aL0[g][c] + bl0);
                outl[row + j + 64] = __float2half(aL1[g][c] + bl1);
                outr[row + j]      = aR0[g][c] + br0;
                outr[row + j + 64] = aR1[g][c] + br1;
            }
        }
    }
}

// ====== per-edge math (16-lane group, 8 channels/lane) =======================
__device__ __forceinline__ void gat_proc(float4 raw, bool valid,
                                         const float* xrd, const float* av,
                                         float* acc, float& sm) {
    const __half2* h = (const __half2*)&raw;
    float v[8];
    float2 f;
    f = __half22float2(h[0]); v[0] = f.x; v[1] = f.y;
    f = __half22float2(h[1]); v[2] = f.x; v[3] = f.y;
    f = __half22float2(h[2]); v[4] = f.x; v[5] = f.y;
    f = __half22float2(h[3]); v[6] = f.x; v[7] = f.y;
    float p = 0.f;
    #pragma unroll
    for (int c = 0; c < 8; c++) {
        float u = v[c] + xrd[c];
        u = (u > 0.f) ? u : NEG_SLOPE * u;
        p += u * av[c];
    }
    p += __shfl_xor(p, 1);
    p += __shfl_xor(p, 2);
    p += __shfl_xor(p, 4);
    p += __shfl_xor(p, 8);
    float w = __expf(fminf(p, 80.f));
    if (!valid) w = 0.f;
    sm += w;
    #pragma unroll
    for (int c = 0; c < 8; c++) acc[c] += w * v[c];
}

// ====== GAT H=4 gather of ONE dst per 16-lane group into LDS row `node` =====
// Round-1 verified structure: chunked csr (16 at a time, prefetch next), 4
// xl-row loads in flight per group. d < 0 => inactive group (zeros written).
// xsh layout: xsh[node * 136 + ch], node in [0,16), ch in [0,128). 4.35 KB.
__device__ __forceinline__ void gat16_to_lds(__half* xsh,
                                             const __half* __restrict__ xl,
                                             const float* __restrict__ xr,
                                             const float* __restrict__ att,
                                             const int* __restrict__ offs,
                                             const int* __restrict__ csr,
                                             const float* __restrict__ bias,
                                             int d, int node) {
    int t = threadIdx.x;
    int lane = t & 63;
    int sub = lane & 15;                      // lane within group
    int lb = lane & 48;                       // group base lane
    float av[8];
    {
        const float4* t4 = (const float4*)(att + sub * 8);
        float4 c = t4[0], e = t4[1];
        av[0]=c.x; av[1]=c.y; av[2]=c.z; av[3]=c.w;
        av[4]=e.x; av[5]=e.y; av[6]=e.z; av[7]=e.w;
    }
    bool ok = d >= 0;
    int i0 = ok ? offs[d] : 0;
    int i1 = ok ? offs[d + 1] : 0;
    int cnt = i1 - i0;

    float xrd[8];
    #pragma unroll
    for (int c = 0; c < 8; c++) xrd[c] = 0.f;
    if (ok) {
        const float4* p4 = (const float4*)(xr + (size_t)d * 128 + sub * 8);
        float4 a = p4[0], b = p4[1];
        xrd[0]=a.x; xrd[1]=a.y; xrd[2]=a.z; xrd[3]=a.w;
        xrd[4]=b.x; xrd[5]=b.y; xrd[6]=b.z; xrd[7]=b.w;
    }
    float acc[8];
    #pragma unroll
    for (int c = 0; c < 8; c++) acc[c] = 0.f;
    float sm = 0.f;

    // first csr chunk (16 edges, one coalesced 64B load per group)
    int myv = (sub < cnt) ? csr[i0 + sub] : 0;
    for (int c0 = 0; c0 < cnt; c0 += 16) {
        // prefetch next chunk's indices while processing current
        int myv_nxt = (c0 + 16 + sub < cnt) ? csr[i0 + c0 + 16 + sub] : 0;
        int rem = min(cnt - c0, 16);
        for (int k = 0; k < rem; k += 4) {
            int s0 = __shfl(myv, lb + k + 0);
            int s1 = __shfl(myv, lb + k + 1);
            int s2 = __shfl(myv, lb + k + 2);
            int s3 = __shfl(myv, lb + k + 3);
            float4 r0 = *(const float4*)(xl + (size_t)s0 * 128 + sub * 8);
            float4 r1 = *(const float4*)(xl + (size_t)s1 * 128 + sub * 8);
            float4 r2 = *(const float4*)(xl + (size_t)s2 * 128 + sub * 8);
            float4 r3 = *(const float4*)(xl + (size_t)s3 * 128 + sub * 8);
            gat_proc(r0, true,        xrd, av, acc, sm);
            gat_proc(r1, k + 1 < rem, xrd, av, acc, sm);
            gat_proc(r2, k + 2 < rem, xrd, av, acc, sm);
            gat_proc(r3, k + 3 < rem, xrd, av, acc, sm);
        }
        myv = myv_nxt;
    }

    // acc is already the full per-dst sum (group's 16 lanes cover 128 ch)
    int ch = sub * 8;
    if (ok) {
        float inv = 1.f / (sm + 1e-16f);
        #pragma unroll
        for (int c = 0; c < 8; c += 2) {
            __half2 hv;
            hv.x = __float2half(fmaxf(acc[c]     * inv + bias[ch + c],     0.f));
            hv.y = __float2half(fmaxf(acc[c + 1] * inv + bias[ch + c + 1], 0.f));
            *(__half2*)&xsh[node * 136 + ch + c] = hv;
        }
    } else {
        // keep MFMA inputs clean for unused rows
        #pragma unroll
        for (int c = 0; c < 8; c += 2)
            *(__half2*)&xsh[node * 136 + ch + c] = __half2{__half(0.f), __half(0.f)};
    }
}

// ====== fused: conv1 gather (16-dst tile) -> conv2 dual linear via MFMA ======
// Extra block (blockIdx == GT) builds the focal-neighborhood dst list L for
// the sparse global-GAT stage (k_gatling): L = concat of focal csr ranges.
__launch_bounds__(256)
__global__ void k_gatlin(const __half* __restrict__ xl, const float* __restrict__ xr,
                         const float* __restrict__ att,
                         const int* __restrict__ offs, const int* __restrict__ csr,
                         const float* __restrict__ bias,
                         const __half* __restrict__ Wlt, const float* __restrict__ bl,
                         const __half* __restrict__ Wrt, const float* __restrict__ br,
                         __half* __restrict__ outl, float* __restrict__ outr, int N,
                         const int* __restrict__ focal, int B,
                         int* __restrict__ L, int* __restrict__ Lcnt, int GT) {
    if (blockIdx.x >= GT) {
        int t = threadIdx.x;
        if (t < B) {
            int f = focal[t];
            int j0 = offs[f], j1 = offs[f + 1];
            int base = atomicAdd(Lcnt, j1 - j0);
            for (int j = j0; j < j1; j++) L[base + (j - j0)] = csr[j];
        }
        return;
    }
    __shared__ __align__(16) __half xsh[16 * 136];
    int nb = blockIdx.x * 16;
    int t = threadIdx.x;
    int lane = t & 63, wv = t >> 6;
    int quad = lane >> 4, n16 = lane & 15;
    {
        int node = wv * 4 + quad;
        int dd = nb + node;
        gat16_to_lds(xsh, xl, xr, att, offs, csr, bias, (dd < N) ? dd : -1, node);
    }
    __syncthreads();

    // A fragments: A[m=lane&15][k=quad*8+i], 4 k-tiles of 32
    f16x8 a[4];
    #pragma unroll
    for (int kt = 0; kt < 4; kt++)
        a[kt] = *(const f16x8*)&xsh[n16 * 136 + kt * 32 + quad * 8];

    int j0 = wv * 32;   // this wave's 32 output columns (two 16-tiles), for L and R
    f32x4 aL0 = {0.f,0.f,0.f,0.f}, aL1 = {0.f,0.f,0.f,0.f};
    f32x4 aR0 = {0.f,0.f,0.f,0.f}, aR1 = {0.f,0.f,0.f,0.f};
    #pragma unroll
    for (int kt = 0; kt < 4; kt++) {
        int ko = kt * 32 + quad * 8;
        f16x8 b0 = *(const f16x8*)&Wlt[(size_t)(j0 + n16) * 128 + ko];
        f16x8 b1 = *(const f16x8*)&Wlt[(size_t)(j0 + 16 + n16) * 128 + ko];
        f16x8 b2 = *(const f16x8*)&Wrt[(size_t)(j0 + n16) * 128 + ko];
        f16x8 b3 = *(const f16x8*)&Wrt[(size_t)(j0 + 16 + n16) * 128 + ko];
        aL0 = __builtin_amdgcn_mfma_f32_16x16x32_f16(a[kt], b0, aL0, 0, 0, 0);
        aL1 = __builtin_amdgcn_mfma_f32_16x16x32_f16(a[kt], b1, aL1, 0, 0, 0);
        aR0 = __builtin_amdgcn_mfma_f32_16x16x32_f16(a[kt], b2, aR0, 0, 0, 0);
        aR1 = __builtin_amdgcn_mfma_f32_16x16x32_f16(a[kt], b3, aR1, 0, 0, 0);
    }
    float blj0 = bl[j0 + n16], blj1 = bl[j0 + 16 + n16];
    float brj0 = br[j0 + n16], brj1 = br[j0 + 16 + n16];
    #pragma unroll
    for (int r = 0; r < 4; r++) {
        int node = quad * 4 + r;        // D row = node
        if (nb + node >= N) continue;
        size_t row = (size_t)(nb + node) * 128;
        outl[row + j0 + n16]      = __float2half(aL0[r] + blj0);
        outl[row + j0 + 16 + n16] = __float2half(aL1[r] + blj1);
        outr[row + j0 + n16]      = aR0[r] + brj0;
        outr[row + j0 + 16 + n16] = aR1[r] + brj1;
    }
}

// ====== sparse: conv2 gather + global linear ONLY at focal-needed dsts =======
// global_features is consumed only at focal nodes; the global-GAT there reads
// xl_g at csr-sources of focal edges and xr_g at focal (in L via self-loops).
// So conv2-gather+global-linear runs over L (~B*deg ~= 1100 dsts), not N.
__launch_bounds__(256)
__global__ void k_gatling(const __half* __restrict__ xl, const float* __restrict__ xr,
                          const float* __restrict__ att,
                          const int* __restrict__ offs, const int* __restrict__ csr,
                          const float* __restrict__ bias,
                          const __half* __restrict__ Wlt, const float* __restrict__ bl,
                          const __half* __restrict__ Wrt, const float* __restrict__ br,
                          __half* __restrict__ outl, float* __restrict__ outr,
                          const int* __restrict__ L, const int* __restrict__ Lcnt) {
    __shared__ __align__(16) __half xsh[16 * 136];
    int total = *Lcnt;
    int t = threadIdx.x;
    int lane = t & 63, wv = t >> 6;
    int quad = lane >> 4, n16 = lane & 15;

    for (int tile = blockIdx.x; tile * 16 < total; tile += gridDim.x) {
        if (tile != (int)blockIdx.x) __syncthreads();   // xsh reuse guard
        int node = wv * 4 + quad;
        int idx = tile * 16 + node;
        int d = (idx < total) ? L[idx] : -1;
        gat16_to_lds(xsh, xl, xr, att, offs, csr, bias, d, node);
        __syncthreads();

        f16x8 a[4];
        #pragma unroll
        for (int kt = 0; kt < 4; kt++)
            a[kt] = *(const f16x8*)&xsh[n16 * 136 + kt * 32 + quad * 8];

        // wave -> one 16x16 tile: wv 0: L j0=0; 1: L j0=16; 2: R j0=0; 3: R j0=16
        const __half* Wt = (wv < 2) ? Wlt : Wrt;
        int j0 = (wv & 1) * 16;
        f32x4 accv = {0.f,0.f,0.f,0.f};
        #pragma unroll
        for (int kt = 0; kt < 4; kt++) {
            f16x8 b = *(const f16x8*)&Wt[(size_t)(j0 + n16) * 128 + kt * 32 + quad * 8];
            accv = __builtin_amdgcn_mfma_f32_16x16x32_f16(a[kt], b, accv, 0, 0, 0);
        }
        float bj = ((wv < 2) ? bl : br)[j0 + n16];
        #pragma unroll
        for (int r = 0; r < 4; r++) {
            int nn = quad * 4 + r;
            int gidx = tile * 16 + nn;
            if (gidx >= total) continue;
            int gd = L[gidx];              // duplicates write identical values
            size_t row = (size_t)gd * 32;
            if (wv < 2) outl[row + j0 + n16] = __float2half(accv[r] + bj);
            else        outr[row + j0 + n16] = accv[r] + bj;
        }
    }
}

// ===== tail: global-GAT gather for the 64 FOCAL dsts only + output head =====
__launch_bounds__(64)
__global__ void k_tailf(const __half* __restrict__ xl, const float* __restrict__ xr,
                        const float* __restrict__ att,
                        const int* __restrict__ offs, const int* __restrict__ csr,
                        const float* __restrict__ gb, const int* __restrict__ focal,
                        const float* __restrict__ clf, const float* __restrict__ clW,
                        const float* __restrict__ clb, const float* __restrict__ fcW,
                        const float* __restrict__ fcb, void* __restrict__ out,
                        const int* __restrict__ flag) {
    __shared__ float comb[64];
    __shared__ float ssb[2];
    int b = blockIdx.x;
    int t = threadIdx.x;                  // 64
    int d = focal[b];
    int grp = t >> 3, sub = t & 7;        // 8 edge-groups x 8 lanes (4 ch each)
    int i0 = offs[d], i1 = offs[d + 1];

    float xrd[4], av[4], acc[4];
    {
        float4 a = *(const float4*)(xr + (size_t)d * 32 + sub * 4);
        xrd[0]=a.x; xrd[1]=a.y; xrd[2]=a.z; xrd[3]=a.w;
        float4 c = *(const float4*)(att + sub * 4);
        av[0]=c.x; av[1]=c.y; av[2]=c.z; av[3]=c.w;
    }
    #pragma unroll
    for (int c = 0; c < 4; c++) acc[c] = 0.f;
    float sm = 0.f;

    for (int i = i0 + grp; i < i1; i += 8) {
        float2 raw = *(const float2*)(xl + (size_t)csr[i] * 32 + sub * 4);
        const __half2* h = (const __half2*)&raw;
        float v[4];
        float2 f;
        f = __half22float2(h[0]); v[0] = f.x; v[1] = f.y;
        f = __half22float2(h[1]); v[2] = f.x; v[3] = f.y;
        float p = 0.f;
        #pragma unroll
        for (int c = 0; c < 4; c++) {
            float u = v[c] + xrd[c];
            u = (u > 0.f) ? u : NEG_SLOPE * u;
            p += u * av[c];
        }
        p += __shfl_xor(p, 1);
        p += __shfl_xor(p, 2);
        p += __shfl_xor(p, 4);
        float w = __expf(fminf(p, 80.f));
        sm += w;
        #pragma unroll
        for (int c = 0; c < 4; c++) acc[c] += w * v[c];
    }
    // merge 8 edge-groups
    sm += __shfl_xor(sm, 8); sm += __shfl_xor(sm, 16); sm += __shfl_xor(sm, 32);
    #pragma unroll
    for (int c = 0; c < 4; c++) {
        acc[c] += __shfl_xor(acc[c], 8);
        acc[c] += __shfl_xor(acc[c], 16);
        acc[c] += __shfl_xor(acc[c], 32);
    }
    if (grp == 0) {
        float inv = 1.f / (sm + 1e-16f);
        #pragma unroll
        for (int c = 0; c < 4; c++)
            comb[sub * 4 + c] = fmaxf(acc[c] * inv + gb[sub * 4 + c], 0.f);
    }
    if (t < 2) {
        float s = 0.f;
        for (int l = 0; l < 50; l++) s += clf[(size_t)b * 100 + l * 2 + t];
        ssb[t] = s / 50.f;
    }
    __syncthreads();
    if (t < 32) comb[32 + t] = ssb[0] * clW[t] + ssb[1] * clW[32 + t] + clb[t];
    __syncthreads();
    if (t < 60) {
        float a2 = fcb[t];
        #pragma unroll 16
        for (int k = 0; k < 64; k++) a2 += comb[k] * fcW[k * 60 + t];
        if (flag[0]) ((float*)out)[b * 60 + t] = a2;
        else ((bf16*)out)[b * 60 + t] = __float2bfloat16(a2);
    }
}

extern "C" void kernel_launch(void* const* d_in, const int* in_sizes, int n_in,
                              void* d_out, int out_size, void* d_ws, size_t ws_size,
                              hipStream_t stream) {
    const int* edge  = (const int*)d_in[1];
    const int* focal = (const int*)d_in[5];

    const int N = in_sizes[0] / 100;   // 20000
    const int E = in_sizes[1] / 2;     // 320000
    const int B = in_sizes[5];         // 64
    const int EA = E + N;
    const int* srcArr = edge;
    const int* dstArr = edge + E;

    // ---- conversion table: weights + centerlines -> fp32 in ws (x stays raw)
    const int idxs[NSEG] = {7,8,9,10,11,12,13,14,15,16,17,18,19,20,
                            35,36,37,38,39,40,41,42,43,44, 6};
    float* base = (float*)d_ws;
    int* flag = (int*)base;            // base[0..15] reserved
    float* wf = base + 16;
    Tab tab;
    int off[NSEG];
    int o = 0;
    for (int i = 0; i < NSEG; i++) {
        tab.s[i].src = d_in[idxs[i]];
        tab.s[i].n   = in_sizes[idxs[i]];
        tab.s[i].off = o;
        off[i] = o;
        o += in_sizes[idxs[i]];
    }
    const float* aeW  = wf + off[0],  *aeb  = wf + off[1];
    const float* a1Wl = wf + off[2],  *a1bl = wf + off[3];
    const float* a1Wr = wf + off[4],  *a1br = wf + off[5];
    const float* a1att= wf + off[6],  *a1b  = wf + off[7];
    const float* a2bl = wf + off[9];
    const float* a2br = wf + off[11];
    const float* a2att= wf + off[12], *a2b  = wf + off[13];
    const float* clW  = wf + off[14], *clb  = wf + off[15];
    const float* gbl  = wf + off[17];
    const float* gbr  = wf + off[19];
    const float* gatt = wf + off[20], *gb   = wf + off[21];
    const float* fcW  = wf + off[22], *fcb  = wf + off[23];
    const float* clf  = wf + off[24];

    // ---- remaining workspace (keep 16B alignment) ----
    float* p = wf + o + ((4 - (o & 3)) & 3);
    size_t N128 = (size_t)N * 128;
    __half* hxl1 = (__half*)p;      p += (size_t)N * 64;    // conv1 xl fp16 [N,128]; later global xl [N,32]
    float* fB1  = p;                p += N128;              // conv1 xr fp32; later global xrg [N,32]
    __half* hxl2 = (__half*)p;      p += (size_t)N * 64;    // conv2 xl fp16 [N,128]
    float* fB2  = p;                p += N128;              // conv2 xr fp32
    int* deg    = (int*)p;          // [N]
    int* st     = deg + N;          // [32] scan lookback state; st[30] = Lcnt
    int* offs   = st + 32;          // N+1
    int* rank   = offs + N + 1;     // EA
    int* csr    = rank + EA;        // EA (src node ids)
    // transposed f16 weights (16B aligned)
    uintptr_t up = (uintptr_t)(csr + EA);
    up = (up + 15) & ~(uintptr_t)15;
    __half* a2Wlt = (__half*)up;    // [128][128]
    __half* a2Wrt = a2Wlt + 16384;  // [128][128]
    __half* gWlt  = a2Wrt + 16384;  // [32][128]
    __half* gWrt  = gWlt + 4096;    // [32][128]
    int* Lbuf = (int*)(gWrt + 4096);   // focal-neighborhood dst list (<= EA)
    int* Lcnt = st + 30;               // zeroed by the memset below

    const int NB = (N + 1023) / 1024;          // scan tiles (20)
    const int EB = N / 32;                     // embedlin blocks (625)
    const int FBLK = (EA + 255) / 256;         // fill blocks
    const int GT = (N + 15) / 16;              // fused gather+linear tiles (1250)

    // ---- zero deg + scan-state + Lcnt via SDMA ----
    hipMemsetAsync(deg, 0, (size_t)(N + 32) * sizeof(int), stream);
    // ---- convert weights (+ f16 transposed) + merged dtype-detect +
    //      degree count with rank capture ----
    k_convert<<<256, 256, 0, stream>>>(tab, wf, (const unsigned short*)d_in[0], flag,
                                       dstArr, E, N, deg, rank,
                                       d_in[15], d_in[17], d_in[37], d_in[39],
                                       a2Wlt, a2Wrt, gWlt, gWrt);
    // ---- single-kernel lookback scan ----
    k_scanf<<<NB, 1024, 0, stream>>>(deg, offs, N, st, NB);
    // ---- CSR fill (rank trick) + fused embed+conv1-linear -> hxl1/fB1 ----
    k_fill_embedlin<<<EB + FBLK, 256, 0, stream>>>(srcArr, dstArr, E, N, offs, rank, csr,
                                                   d_in[0], flag, aeW, aeb,
                                                   a1Wl, a1bl, a1Wr, a1br, hxl1, fB1, EB);
    // ---- conv1 gather + conv2 linear (MFMA) -> hxl2/fB2; +1 block builds L --
    k_gatlin<<<GT + 1, 256, 0, stream>>>(hxl1, fB1, a1att, offs, csr, a1b,
                                         a2Wlt, a2bl, a2Wrt, a2br, hxl2, fB2, N,
                                         focal, B, Lbuf, Lcnt, GT);
    // ---- SPARSE conv2 gather + global linear over L only -> hxl1/fB1 -------
    k_gatling<<<128, 256, 0, stream>>>(hxl2, fB2, a2att, offs, csr, a2b,
                                       gWlt, gbl, gWrt, gbr, hxl1, fB1, Lbuf, Lcnt);
    // ---- tail: global gather for the 64 focal dsts + head ----
    k_tailf<<<B, 64, 0, stream>>>(hxl1, fB1, gatt, offs, csr, gb, focal,
                                  clf, clW, clb, fcW, fcb, d_out, flag);
}

// Round 8
// 234.022 us; speedup vs baseline: 2.2860x; 1.0902x over previous
//
#include <hip/hip_runtime.h>
#include <hip/hip_bf16.h>
#include <hip/hip_fp16.h>
#include <math.h>

typedef __hip_bfloat16 bf16;
#define NEG_SLOPE 0.2f

typedef _Float16 f16x8 __attribute__((ext_vector_type(8)));
typedef float f32x4 __attribute__((ext_vector_type(4)));

#define NSEG 25
struct Seg { const void* src; int n; int off; };
struct Tab { Seg s[NSEG]; };

__device__ __forceinline__ float ldconv(const void* src, int i, int f32mode) {
    return f32mode ? ((const float*)src)[i]
                   : __bfloat162float(((const bf16*)src)[i]);
}

// ====== convert weights fp32 + transposed f16 weights + DIRECT fixed-stride
// CSR build (no scan, no fill pass). csrF[d*64 + r] = src, r = capture rank;
// overflow r>=64 (never on this input; correctness path) goes to spill list.
// dtype-detect merged: every block recomputes the census locally.
__global__ void k_convert(Tab tab, float* __restrict__ dst,
                          const unsigned short* __restrict__ xdet, int* __restrict__ flag,
                          const int* __restrict__ srcArr, const int* __restrict__ dstArr,
                          int E, int N,
                          int* __restrict__ deg, int* __restrict__ csrF,
                          int* __restrict__ spillD, int* __restrict__ spillS,
                          int* __restrict__ spillCnt,
                          const void* a2WlS, const void* a2WrS,
                          const void* gWlS, const void* gWrS,
                          __half* __restrict__ a2Wlt, __half* __restrict__ a2Wrt,
                          __half* __restrict__ gWlt, __half* __restrict__ gWrt) {
    __shared__ int cnt;
    if (threadIdx.x == 0) cnt = 0;
    __syncthreads();
    int local = 0;
    for (int i = threadIdx.x; i < 2048; i += blockDim.x) {
        unsigned short w = xdet[2 * i];
        int e = (w >> 7) & 0xFF;
        if (e >= 0x90) local++;
    }
    atomicAdd(&cnt, local);
    __syncthreads();
    int f32mode = (cnt > 100) ? 1 : 0;          // same verdict in every block
    if (blockIdx.x == 0 && threadIdx.x == 0) flag[0] = f32mode;

    int gid = blockIdx.x * blockDim.x + threadIdx.x;
    int gsz = gridDim.x * blockDim.x;
    for (int s = 0; s < NSEG; s++) {
        Seg sg = tab.s[s];
        for (int i = gid; i < sg.n; i += gsz) {
            dst[sg.off + i] = ldconv(sg.src, i, f32mode);
        }
    }
    // transposed f16 weights: Wt[j][k] = W[k][j]
    for (int i = gid; i < 128 * 128; i += gsz) {
        int k = i >> 7, j = i & 127;
        a2Wlt[(size_t)j * 128 + k] = __float2half(ldconv(a2WlS, i, f32mode));
        a2Wrt[(size_t)j * 128 + k] = __float2half(ldconv(a2WrS, i, f32mode));
    }
    for (int i = gid; i < 128 * 32; i += gsz) {
        int k = i >> 5, j = i & 31;
        gWlt[(size_t)j * 128 + k] = __float2half(ldconv(gWlS, i, f32mode));
        gWrt[(size_t)j * 128 + k] = __float2half(ldconv(gWrS, i, f32mode));
    }
    int EA = E + N;
    for (int e = gid; e < EA; e += gsz) {
        int d, s;
        if (e < E) { d = dstArr[e]; s = srcArr[e]; } else { d = s = e - E; }
        int r = atomicAdd(&deg[d], 1);
        if (r < 64) {
            csrF[(size_t)d * 64 + r] = s;
        } else {
            int o = atomicAdd(spillCnt, 1);
            spillD[o] = d; spillS[o] = s;
        }
    }
}

// ====== embed + conv1 linear (32 nodes per block; no CSR work here) =========
__launch_bounds__(256)
__global__ void k_embedlin(const void* __restrict__ xraw, const int* __restrict__ flag,
                           int N,
                           const float* __restrict__ aeW, const float* __restrict__ aeb,
                           const float* __restrict__ Wl, const float* __restrict__ bl,
                           const float* __restrict__ Wr, const float* __restrict__ br,
                           __half* __restrict__ outl, float* __restrict__ outr) {
    __shared__ float xs[100 * 36];
    __shared__ float axs[32 * 36];
    constexpr int NTP = 36;
    int t = threadIdx.x, nb = blockIdx.x * 32;
    if (flag[0]) {
        const float4* x4 = (const float4*)xraw;
        for (int idx = t; idx < 32 * 25; idx += 256) {
            int node = idx / 25, k4 = idx % 25;
            float4 v = x4[(size_t)(nb + node) * 25 + k4];
            xs[(k4 * 4 + 0) * NTP + node] = v.x;
            xs[(k4 * 4 + 1) * NTP + node] = v.y;
            xs[(k4 * 4 + 2) * NTP + node] = v.z;
            xs[(k4 * 4 + 3) * NTP + node] = v.w;
        }
    } else {
        const ushort4* xu = (const ushort4*)xraw;
        for (int idx = t; idx < 32 * 25; idx += 256) {
            int node = idx / 25, k4 = idx % 25;
            ushort4 u = xu[(size_t)(nb + node) * 25 + k4];
            xs[(k4 * 4 + 0) * NTP + node] = __uint_as_float((unsigned)u.x << 16);
            xs[(k4 * 4 + 1) * NTP + node] = __uint_as_float((unsigned)u.y << 16);
            xs[(k4 * 4 + 2) * NTP + node] = __uint_as_float((unsigned)u.z << 16);
            xs[(k4 * 4 + 3) * NTP + node] = __uint_as_float((unsigned)u.w << 16);
        }
    }
    __syncthreads();
    {
        int j = t & 31, g0 = t >> 5;
        float a0 = 0.f, a1 = 0.f, a2 = 0.f, a3 = 0.f;
        #pragma unroll 10
        for (int k = 0; k < 100; k++) {
            float w = aeW[k * 32 + j];
            const float4 xv = *(const float4*)&xs[k * NTP + g0 * 4];
            a0 += w * xv.x; a1 += w * xv.y; a2 += w * xv.z; a3 += w * xv.w;
        }
        float bj = aeb[j];
        axs[j * NTP + g0 * 4 + 0] = fmaxf(a0 + bj, 0.f);
        axs[j * NTP + g0 * 4 + 1] = fmaxf(a1 + bj, 0.f);
        axs[j * NTP + g0 * 4 + 2] = fmaxf(a2 + bj, 0.f);
        axs[j * NTP + g0 * 4 + 3] = fmaxf(a3 + bj, 0.f);
    }
    __syncthreads();
    {
        int j = t & 63, g0 = t >> 6;
        float aL0[2][4], aL1[2][4], aR0[2][4], aR1[2][4];
        #pragma unroll
        for (int g = 0; g < 2; g++)
            #pragma unroll
            for (int c = 0; c < 4; c++) { aL0[g][c]=0.f; aL1[g][c]=0.f; aR0[g][c]=0.f; aR1[g][c]=0.f; }
        #pragma unroll 4
        for (int k = 0; k < 32; k++) {
            float wl0 = Wl[k * 128 + j];
            float wl1 = Wl[k * 128 + j + 64];
            float wr0 = Wr[k * 128 + j];
            float wr1 = Wr[k * 128 + j + 64];
            #pragma unroll
            for (int g = 0; g < 2; g++) {
                const float4 xv = *(const float4*)&axs[k * NTP + (g0 + g * 4) * 4];
                aL0[g][0] += wl0 * xv.x; aL0[g][1] += wl0 * xv.y; aL0[g][2] += wl0 * xv.z; aL0[g][3] += wl0 * xv.w;
                aL1[g][0] += wl1 * xv.x; aL1[g][1] += wl1 * xv.y; aL1[g][2] += wl1 * xv.z; aL1[g][3] += wl1 * xv.w;
                aR0[g][0] += wr0 * xv.x; aR0[g][1] += wr0 * xv.y; aR0[g][2] += wr0 * xv.z; aR0[g][3] += wr0 * xv.w;
                aR1[g][0] += wr1 * xv.x; aR1[g][1] += wr1 * xv.y; aR1[g][2] += wr1 * xv.z; aR1[g][3] += wr1 * xv.w;
            }
        }
        float bl0 = bl[j], bl1 = bl[j + 64], br0 = br[j], br1 = br[j + 64];
        #pragma unroll
        for (int g = 0; g < 2; g++) {
            int n0 = nb + (g0 + g * 4) * 4;
            #pragma unroll
            for (int c = 0; c < 4; c++) {
                size_t row = (size_t)(n0 + c) * 128;
                outl[row + j]      = __float2half(aL0[g][c] + bl0);
                outl[row + j + 64] = __float2half(aL1[g][c] + bl1);
                outr[row + j]      = aR0[g][c] + br0;
                outr[row + j + 64] = aR1[g][c] + br1;
            }
        }
    }
}

// ====== per-edge math (16-lane group, 8 channels/lane) =======================
__device__ __forceinline__ void gat_proc(float4 raw, bool valid,
                                         const float* xrd, const float* av,
                                         float* acc, float& sm) {
    const __half2* h = (const __half2*)&raw;
    float v[8];
    float2 f;
    f = __half22float2(h[0]); v[0] = f.x; v[1] = f.y;
    f = __half22float2(h[1]); v[2] = f.x; v[3] = f.y;
    f = __half22float2(h[2]); v[4] = f.x; v[5] = f.y;
    f = __half22float2(h[3]); v[6] = f.x; v[7] = f.y;
    float p = 0.f;
    #pragma unroll
    for (int c = 0; c < 8; c++) {
        float u = v[c] + xrd[c];
        u = (u > 0.f) ? u : NEG_SLOPE * u;
        p += u * av[c];
    }
    p += __shfl_xor(p, 1);
    p += __shfl_xor(p, 2);
    p += __shfl_xor(p, 4);
    p += __shfl_xor(p, 8);
    float w = __expf(fminf(p, 80.f));
    if (!valid) w = 0.f;
    sm += w;
    #pragma unroll
    for (int c = 0; c < 8; c++) acc[c] += w * v[c];
}

// ====== GAT H=4 gather of ONE dst per 16-lane group into LDS row `node` =====
// Fixed-stride CSR: row base = d*64, count = deg[d]; spill path for deg>64
// (correctness only; never taken on this input). d < 0 => zeros written.
// xsh layout: xsh[node * 136 + ch], node in [0,16), ch in [0,128). 4.35 KB.
__device__ __forceinline__ void gat16_to_lds(__half* xsh,
                                             const __half* __restrict__ xl,
                                             const float* __restrict__ xr,
                                             const float* __restrict__ att,
                                             const int* __restrict__ deg,
                                             const int* __restrict__ csrF,
                                             const int* __restrict__ spillD,
                                             const int* __restrict__ spillS,
                                             const int* __restrict__ spillCnt,
                                             const float* __restrict__ bias,
                                             int d, int node) {
    int t = threadIdx.x;
    int lane = t & 63;
    int sub = lane & 15;                      // lane within group
    int lb = lane & 48;                       // group base lane
    float av[8];
    {
        const float4* t4 = (const float4*)(att + sub * 8);
        float4 c = t4[0], e = t4[1];
        av[0]=c.x; av[1]=c.y; av[2]=c.z; av[3]=c.w;
        av[4]=e.x; av[5]=e.y; av[6]=e.z; av[7]=e.w;
    }
    bool ok = d >= 0;
    int cnt = ok ? deg[d] : 0;
    int cmain = cnt < 64 ? cnt : 64;
    size_t i0 = (size_t)(ok ? d : 0) * 64;

    float xrd[8];
    #pragma unroll
    for (int c = 0; c < 8; c++) xrd[c] = 0.f;
    if (ok) {
        const float4* p4 = (const float4*)(xr + (size_t)d * 128 + sub * 8);
        float4 a = p4[0], b = p4[1];
        xrd[0]=a.x; xrd[1]=a.y; xrd[2]=a.z; xrd[3]=a.w;
        xrd[4]=b.x; xrd[5]=b.y; xrd[6]=b.z; xrd[7]=b.w;
    }
    float acc[8];
    #pragma unroll
    for (int c = 0; c < 8; c++) acc[c] = 0.f;
    float sm = 0.f;

    // first csr chunk (16 edges, one coalesced 64B load per group)
    int myv = (sub < cmain) ? csrF[i0 + sub] : 0;
    for (int c0 = 0; c0 < cmain; c0 += 16) {
        // prefetch next chunk's indices while processing current
        int myv_nxt = (c0 + 16 + sub < cmain) ? csrF[i0 + c0 + 16 + sub] : 0;
        int rem = min(cmain - c0, 16);
        for (int k = 0; k < rem; k += 4) {
            int s0 = __shfl(myv, lb + k + 0);
            int s1 = __shfl(myv, lb + k + 1);
            int s2 = __shfl(myv, lb + k + 2);
            int s3 = __shfl(myv, lb + k + 3);
            float4 r0 = *(const float4*)(xl + (size_t)s0 * 128 + sub * 8);
            float4 r1 = *(const float4*)(xl + (size_t)s1 * 128 + sub * 8);
            float4 r2 = *(const float4*)(xl + (size_t)s2 * 128 + sub * 8);
            float4 r3 = *(const float4*)(xl + (size_t)s3 * 128 + sub * 8);
            gat_proc(r0, true,        xrd, av, acc, sm);
            gat_proc(r1, k + 1 < rem, xrd, av, acc, sm);
            gat_proc(r2, k + 2 < rem, xrd, av, acc, sm);
            gat_proc(r3, k + 3 < rem, xrd, av, acc, sm);
        }
        myv = myv_nxt;
    }
    // rare spill path (deg > 64): linear scan of the overflow list
    if (cnt > 64) {
        int stot = *spillCnt;
        for (int j = 0; j < stot; j++) {
            if (spillD[j] == d) {
                float4 r = *(const float4*)(xl + (size_t)spillS[j] * 128 + sub * 8);
                gat_proc(r, true, xrd, av, acc, sm);
            }
        }
    }

    // acc is already the full per-dst sum (group's 16 lanes cover 128 ch)
    int ch = sub * 8;
    if (ok) {
        float inv = 1.f / (sm + 1e-16f);
        #pragma unroll
        for (int c = 0; c < 8; c += 2) {
            __half2 hv;
            hv.x = __float2half(fmaxf(acc[c]     * inv + bias[ch + c],     0.f));
            hv.y = __float2half(fmaxf(acc[c + 1] * inv + bias[ch + c + 1], 0.f));
            *(__half2*)&xsh[node * 136 + ch + c] = hv;
        }
    } else {
        // keep MFMA inputs clean for unused rows
        #pragma unroll
        for (int c = 0; c < 8; c += 2)
            *(__half2*)&xsh[node * 136 + ch + c] = __half2{__half(0.f), __half(0.f)};
    }
}

// ====== fused: conv1 gather (16-dst tile) -> conv2 dual linear via MFMA ======
// Extra block (blockIdx == GT) builds the focal-neighborhood dst list L for
// the sparse global-GAT stage (k_gatling): L = concat of focal source lists.
__launch_bounds__(256)
__global__ void k_gatlin(const __half* __restrict__ xl, const float* __restrict__ xr,
                         const float* __restrict__ att,
                         const int* __restrict__ deg, const int* __restrict__ csrF,
                         const int* __restrict__ spillD, const int* __restrict__ spillS,
                         const int* __restrict__ spillCnt,
                         const float* __restrict__ bias,
                         const __half* __restrict__ Wlt, const float* __restrict__ bl,
                         const __half* __restrict__ Wrt, const float* __restrict__ br,
                         __half* __restrict__ outl, float* __restrict__ outr, int N,
                         const int* __restrict__ focal, int B,
                         int* __restrict__ L, int* __restrict__ Lcnt, int GT) {
    if (blockIdx.x >= GT) {
        int t = threadIdx.x;
        if (t < B) {
            int f = focal[t];
            int cf = deg[f];
            int cm = cf < 64 ? cf : 64;
            int base = atomicAdd(Lcnt, cf);
            for (int j = 0; j < cm; j++) L[base + j] = csrF[(size_t)f * 64 + j];
            if (cf > 64) {
                int k = cm;
                int stot = *spillCnt;
                for (int j = 0; j < stot; j++)
                    if (spillD[j] == f) L[base + k++] = spillS[j];
            }
        }
        return;
    }
    __shared__ __align__(16) __half xsh[16 * 136];
    int nb = blockIdx.x * 16;
    int t = threadIdx.x;
    int lane = t & 63, wv = t >> 6;
    int quad = lane >> 4, n16 = lane & 15;
    {
        int node = wv * 4 + quad;
        int dd = nb + node;
        gat16_to_lds(xsh, xl, xr, att, deg, csrF, spillD, spillS, spillCnt,
                     bias, (dd < N) ? dd : -1, node);
    }
    __syncthreads();

    // A fragments: A[m=lane&15][k=quad*8+i], 4 k-tiles of 32
    f16x8 a[4];
    #pragma unroll
    for (int kt = 0; kt < 4; kt++)
        a[kt] = *(const f16x8*)&xsh[n16 * 136 + kt * 32 + quad * 8];

    int j0 = wv * 32;   // this wave's 32 output columns (two 16-tiles), for L and R
    f32x4 aL0 = {0.f,0.f,0.f,0.f}, aL1 = {0.f,0.f,0.f,0.f};
    f32x4 aR0 = {0.f,0.f,0.f,0.f}, aR1 = {0.f,0.f,0.f,0.f};
    #pragma unroll
    for (int kt = 0; kt < 4; kt++) {
        int ko = kt * 32 + quad * 8;
        f16x8 b0 = *(const f16x8*)&Wlt[(size_t)(j0 + n16) * 128 + ko];
        f16x8 b1 = *(const f16x8*)&Wlt[(size_t)(j0 + 16 + n16) * 128 + ko];
        f16x8 b2 = *(const f16x8*)&Wrt[(size_t)(j0 + n16) * 128 + ko];
        f16x8 b3 = *(const f16x8*)&Wrt[(size_t)(j0 + 16 + n16) * 128 + ko];
        aL0 = __builtin_amdgcn_mfma_f32_16x16x32_f16(a[kt], b0, aL0, 0, 0, 0);
        aL1 = __builtin_amdgcn_mfma_f32_16x16x32_f16(a[kt], b1, aL1, 0, 0, 0);
        aR0 = __builtin_amdgcn_mfma_f32_16x16x32_f16(a[kt], b2, aR0, 0, 0, 0);
        aR1 = __builtin_amdgcn_mfma_f32_16x16x32_f16(a[kt], b3, aR1, 0, 0, 0);
    }
    float blj0 = bl[j0 + n16], blj1 = bl[j0 + 16 + n16];
    float brj0 = br[j0 + n16], brj1 = br[j0 + 16 + n16];
    #pragma unroll
    for (int r = 0; r < 4; r++) {
        int node = quad * 4 + r;        // D row = node
        if (nb + node >= N) continue;
        size_t row = (size_t)(nb + node) * 128;
        outl[row + j0 + n16]      = __float2half(aL0[r] + blj0);
        outl[row + j0 + 16 + n16] = __float2half(aL1[r] + blj1);
        outr[row + j0 + n16]      = aR0[r] + brj0;
        outr[row + j0 + 16 + n16] = aR1[r] + brj1;
    }
}

// ====== sparse: conv2 gather + global linear ONLY at focal-needed dsts =======
__launch_bounds__(256)
__global__ void k_gatling(const __half* __restrict__ xl, const float* __restrict__ xr,
                          const float* __restrict__ att,
                          const int* __restrict__ deg, const int* __restrict__ csrF,
                          const int* __restrict__ spillD, const int* __restrict__ spillS,
                          const int* __restrict__ spillCnt,
                          const float* __restrict__ bias,
                          const __half* __restrict__ Wlt, const float* __restrict__ bl,
                          const __half* __restrict__ Wrt, const float* __restrict__ br,
                          __half* __restrict__ outl, float* __restrict__ outr,
                          const int* __restrict__ L, const int* __restrict__ Lcnt) {
    __shared__ __align__(16) __half xsh[16 * 136];
    int total = *Lcnt;
    int t = threadIdx.x;
    int lane = t & 63, wv = t >> 6;
    int quad = lane >> 4, n16 = lane & 15;

    for (int tile = blockIdx.x; tile * 16 < total; tile += gridDim.x) {
        if (tile != (int)blockIdx.x) __syncthreads();   // xsh reuse guard
        int node = wv * 4 + quad;
        int idx = tile * 16 + node;
        int d = (idx < total) ? L[idx] : -1;
        gat16_to_lds(xsh, xl, xr, att, deg, csrF, spillD, spillS, spillCnt,
                     bias, d, node);
        __syncthreads();

        f16x8 a[4];
        #pragma unroll
        for (int kt = 0; kt < 4; kt++)
            a[kt] = *(const f16x8*)&xsh[n16 * 136 + kt * 32 + quad * 8];

        // wave -> one 16x16 tile: wv 0: L j0=0; 1: L j0=16; 2: R j0=0; 3: R j0=16
        const __half* Wt = (wv < 2) ? Wlt : Wrt;
        int j0 = (wv & 1) * 16;
        f32x4 accv = {0.f,0.f,0.f,0.f};
        #pragma unroll
        for (int kt = 0; kt < 4; kt++) {
            f16x8 b = *(const f16x8*)&Wt[(size_t)(j0 + n16) * 128 + kt * 32 + quad * 8];
            accv = __builtin_amdgcn_mfma_f32_16x16x32_f16(a[kt], b, accv, 0, 0, 0);
        }
        float bj = ((wv < 2) ? bl : br)[j0 + n16];
        #pragma unroll
        for (int r = 0; r < 4; r++) {
            int nn = quad * 4 + r;
            int gidx = tile * 16 + nn;
            if (gidx >= total) continue;
            int gd = L[gidx];              // duplicates write identical values
            size_t row = (size_t)gd * 32;
            if (wv < 2) outl[row + j0 + n16] = __float2half(accv[r] + bj);
            else        outr[row + j0 + n16] = accv[r] + bj;
        }
    }
}

// ===== tail: global-GAT gather for the 64 FOCAL dsts only + output head =====
__launch_bounds__(64)
__global__ void k_tailf(const __half* __restrict__ xl, const float* __restrict__ xr,
                        const float* __restrict__ att,
                        const int* __restrict__ deg, const int* __restrict__ csrF,
                        const int* __restrict__ spillD, const int* __restrict__ spillS,
                        const int* __restrict__ spillCnt,
                        const float* __restrict__ gb, const int* __restrict__ focal,
                        const float* __restrict__ clf, const float* __restrict__ clW,
                        const float* __restrict__ clb, const float* __restrict__ fcW,
                        const float* __restrict__ fcb, void* __restrict__ out,
                        const int* __restrict__ flag) {
    __shared__ float comb[64];
    __shared__ float ssb[2];
    int b = blockIdx.x;
    int t = threadIdx.x;                  // 64
    int d = focal[b];
    int grp = t >> 3, sub = t & 7;        // 8 edge-groups x 8 lanes (4 ch each)
    int cnt = deg[d];
    int cm = cnt < 64 ? cnt : 64;
    size_t i0 = (size_t)d * 64;

    float xrd[4], av[4], acc[4];
    {
        float4 a = *(const float4*)(xr + (size_t)d * 32 + sub * 4);
        xrd[0]=a.x; xrd[1]=a.y; xrd[2]=a.z; xrd[3]=a.w;
        float4 c = *(const float4*)(att + sub * 4);
        av[0]=c.x; av[1]=c.y; av[2]=c.z; av[3]=c.w;
    }
    #pragma unroll
    for (int c = 0; c < 4; c++) acc[c] = 0.f;
    float sm = 0.f;

    auto edge = [&](int s) {
        float2 raw = *(const float2*)(xl + (size_t)s * 32 + sub * 4);
        const __half2* h = (const __half2*)&raw;
        float v[4];
        float2 f;
        f = __half22float2(h[0]); v[0] = f.x; v[1] = f.y;
        f = __half22float2(h[1]); v[2] = f.x; v[3] = f.y;
        float p = 0.f;
        #pragma unroll
        for (int c = 0; c < 4; c++) {
            float u = v[c] + xrd[c];
            u = (u > 0.f) ? u : NEG_SLOPE * u;
            p += u * av[c];
        }
        p += __shfl_xor(p, 1);
        p += __shfl_xor(p, 2);
        p += __shfl_xor(p, 4);
        float w = __expf(fminf(p, 80.f));
        sm += w;
        #pragma unroll
        for (int c = 0; c < 4; c++) acc[c] += w * v[c];
    };
    for (int i = grp; i < cm; i += 8) edge(csrF[i0 + i]);
    if (cnt > 64) {                      // rare spill path
        int stot = *spillCnt;
        for (int i = grp; i < stot; i += 8)
            if (spillD[i] == d) edge(spillS[i]);
    }
    // merge 8 edge-groups
    sm += __shfl_xor(sm, 8); sm += __shfl_xor(sm, 16); sm += __shfl_xor(sm, 32);
    #pragma unroll
    for (int c = 0; c < 4; c++) {
        acc[c] += __shfl_xor(acc[c], 8);
        acc[c] += __shfl_xor(acc[c], 16);
        acc[c] += __shfl_xor(acc[c], 32);
    }
    if (grp == 0) {
        float inv = 1.f / (sm + 1e-16f);
        #pragma unroll
        for (int c = 0; c < 4; c++)
            comb[sub * 4 + c] = fmaxf(acc[c] * inv + gb[sub * 4 + c], 0.f);
    }
    if (t < 2) {
        float s = 0.f;
        for (int l = 0; l < 50; l++) s += clf[(size_t)b * 100 + l * 2 + t];
        ssb[t] = s / 50.f;
    }
    __syncthreads();
    if (t < 32) comb[32 + t] = ssb[0] * clW[t] + ssb[1] * clW[32 + t] + clb[t];
    __syncthreads();
    if (t < 60) {
        float a2 = fcb[t];
        #pragma unroll 16
        for (int k = 0; k < 64; k++) a2 += comb[k] * fcW[k * 60 + t];
        if (flag[0]) ((float*)out)[b * 60 + t] = a2;
        else ((bf16*)out)[b * 60 + t] = __float2bfloat16(a2);
    }
}

extern "C" void kernel_launch(void* const* d_in, const int* in_sizes, int n_in,
                              void* d_out, int out_size, void* d_ws, size_t ws_size,
                              hipStream_t stream) {
    const int* edge  = (const int*)d_in[1];
    const int* focal = (const int*)d_in[5];

    const int N = in_sizes[0] / 100;   // 20000
    const int E = in_sizes[1] / 2;     // 320000
    const int B = in_sizes[5];         // 64
    const int EA = E + N;
    const int* srcArr = edge;
    const int* dstArr = edge + E;

    // ---- conversion table: weights + centerlines -> fp32 in ws (x stays raw)
    const int idxs[NSEG] = {7,8,9,10,11,12,13,14,15,16,17,18,19,20,
                            35,36,37,38,39,40,41,42,43,44, 6};
    float* base = (float*)d_ws;
    int* flag = (int*)base;            // base[0..15] reserved
    float* wf = base + 16;
    Tab tab;
    int off[NSEG];
    int o = 0;
    for (int i = 0; i < NSEG; i++) {
        tab.s[i].src = d_in[idxs[i]];
        tab.s[i].n   = in_sizes[idxs[i]];
        tab.s[i].off = o;
        off[i] = o;
        o += in_sizes[idxs[i]];
    }
    const float* aeW  = wf + off[0],  *aeb  = wf + off[1];
    const float* a1Wl = wf + off[2],  *a1bl = wf + off[3];
    const float* a1Wr = wf + off[4],  *a1br = wf + off[5];
    const float* a1att= wf + off[6],  *a1b  = wf + off[7];
    const float* a2bl = wf + off[9];
    const float* a2br = wf + off[11];
    const float* a2att= wf + off[12], *a2b  = wf + off[13];
    const float* clW  = wf + off[14], *clb  = wf + off[15];
    const float* gbl  = wf + off[17];
    const float* gbr  = wf + off[19];
    const float* gatt = wf + off[20], *gb   = wf + off[21];
    const float* fcW  = wf + off[22], *fcb  = wf + off[23];
    const float* clf  = wf + off[24];

    // ---- remaining workspace (keep 16B alignment) ----
    float* p = wf + o + ((4 - (o & 3)) & 3);
    size_t N128 = (size_t)N * 128;
    __half* hxl1 = (__half*)p;      p += (size_t)N * 64;    // conv1 xl fp16 [N,128]; later global xl [N,32]
    float* fB1  = p;                p += N128;              // conv1 xr fp32; later global xrg [N,32]
    __half* hxl2 = (__half*)p;      p += (size_t)N * 64;    // conv2 xl fp16 [N,128]
    float* fB2  = p;                p += N128;              // conv2 xr fp32
    int* deg    = (int*)p;          // [N]
    int* st     = deg + N;          // [32] aux; st[30] = Lcnt, st[29] = spillCnt
    int* csrF   = st + 32;          // [N*64] fixed-stride CSR
    int* spillD = csrF + (size_t)N * 64;  // [EA] overflow dsts (rare)
    int* spillS = spillD + EA;            // [EA] overflow srcs
    // transposed f16 weights (16B aligned)
    uintptr_t up = (uintptr_t)(spillS + EA);
    up = (up + 15) & ~(uintptr_t)15;
    __half* a2Wlt = (__half*)up;    // [128][128]
    __half* a2Wrt = a2Wlt + 16384;  // [128][128]
    __half* gWlt  = a2Wrt + 16384;  // [32][128]
    __half* gWrt  = gWlt + 4096;    // [32][128]
    int* Lbuf = (int*)(gWrt + 4096);   // focal-neighborhood dst list (<= EA)
    int* Lcnt = st + 30;               // zeroed by the memset below
    int* spillCnt = st + 29;           // zeroed by the memset below

    const int EB = N / 32;                     // embedlin blocks (625)
    const int GT = (N + 15) / 16;              // fused gather+linear tiles (1250)

    // ---- zero deg + aux (Lcnt, spillCnt) via SDMA ----
    hipMemsetAsync(deg, 0, (size_t)(N + 32) * sizeof(int), stream);
    // ---- convert weights (+ f16 transposed) + merged dtype-detect +
    //      DIRECT fixed-stride CSR build (no scan, no fill pass) ----
    k_convert<<<256, 256, 0, stream>>>(tab, wf, (const unsigned short*)d_in[0], flag,
                                       srcArr, dstArr, E, N, deg, csrF,
                                       spillD, spillS, spillCnt,
                                       d_in[15], d_in[17], d_in[37], d_in[39],
                                       a2Wlt, a2Wrt, gWlt, gWrt);
    // ---- embed + conv1 linear -> hxl1/fB1 ----
    k_embedlin<<<EB, 256, 0, stream>>>(d_in[0], flag, N, aeW, aeb,
                                       a1Wl, a1bl, a1Wr, a1br, hxl1, fB1);
    // ---- conv1 gather + conv2 linear (MFMA) -> hxl2/fB2; +1 block builds L --
    k_gatlin<<<GT + 1, 256, 0, stream>>>(hxl1, fB1, a1att, deg, csrF,
                                         spillD, spillS, spillCnt, a1b,
                                         a2Wlt, a2bl, a2Wrt, a2br, hxl2, fB2, N,
                                         focal, B, Lbuf, Lcnt, GT);
    // ---- SPARSE conv2 gather + global linear over L only -> hxl1/fB1 -------
    k_gatling<<<128, 256, 0, stream>>>(hxl2, fB2, a2att, deg, csrF,
                                       spillD, spillS, spillCnt, a2b,
                                       gWlt, gbl, gWrt, gbr, hxl1, fB1, Lbuf, Lcnt);
    // ---- tail: global gather for the 64 focal dsts + head ----
    k_tailf<<<B, 64, 0, stream>>>(hxl1, fB1, gatt, deg, csrF,
                                  spillD, spillS, spillCnt, gb, focal,
                                  clf, clW, clb, fcW, fcb, d_out, flag);
}